// Round 1
// baseline (13183.578 us; speedup 1.0000x reference)
//
#include <hip/hip_runtime.h>
#include <hip/hip_bf16.h>
#include <math.h>

typedef short short8 __attribute__((ext_vector_type(8)));
typedef float f32x4 __attribute__((ext_vector_type(4)));
typedef unsigned short ushort_t;
typedef unsigned int uint_t;

#define D_MODEL 768
#define L_LAYERS 6
#define N_TOK 4096   // B*T
#define T_SEQ 2048
#define H_HEADS 12
#define V_VOCAB 32000

// ---------- helpers ----------
__device__ __forceinline__ ushort_t f2b(float f) {
  uint_t u = __builtin_bit_cast(uint_t, f);
  u += 0x7fffu + ((u >> 16) & 1u);   // RNE
  return (ushort_t)(u >> 16);
}

__device__ __forceinline__ void gload_lds16(const void* g, void* l) {
  __builtin_amdgcn_global_load_lds(
      (const __attribute__((address_space(1))) unsigned int*)g,
      (__attribute__((address_space(3))) unsigned int*)l, 16, 0, 0);
}

// ---------- embedding ----------
__global__ void embed_kernel(const int* __restrict__ idx, const float* __restrict__ tok,
                             const float* __restrict__ pos, float* __restrict__ x) {
  int n = blockIdx.x;
  int tok_id = idx[n];
  int t = n & (T_SEQ - 1);
  const float* tr = tok + (size_t)tok_id * D_MODEL;
  const float* pr = pos + (size_t)t * D_MODEL;
  float* xr = x + (size_t)n * D_MODEL;
  for (int k = threadIdx.x; k < D_MODEL; k += 256) xr[k] = tr[k] + pr[k];
}

// ---------- layernorm (fp32 in -> bf16 out) ----------
__global__ void ln_kernel(const float* __restrict__ x, const float* __restrict__ w,
                          const float* __restrict__ b, ushort_t* __restrict__ out) {
  int r = blockIdx.x, tid = threadIdx.x;
  const float* xr = x + (size_t)r * D_MODEL;
  float v0 = xr[tid], v1 = xr[tid + 256], v2 = xr[tid + 512];
  __shared__ float red[8];
  int l = tid & 63, wv = tid >> 6;
  float s = v0 + v1 + v2;
#pragma unroll
  for (int m = 32; m >= 1; m >>= 1) s += __shfl_xor(s, m, 64);
  if (l == 0) red[wv] = s;
  __syncthreads();
  float mean = (red[0] + red[1] + red[2] + red[3]) * (1.f / 768.f);
  float t0 = v0 - mean, t1 = v1 - mean, t2 = v2 - mean;
  float sq = t0 * t0 + t1 * t1 + t2 * t2;
#pragma unroll
  for (int m = 32; m >= 1; m >>= 1) sq += __shfl_xor(sq, m, 64);
  if (l == 0) red[4 + wv] = sq;
  __syncthreads();
  float var = (red[4] + red[5] + red[6] + red[7]) * (1.f / 768.f);
  float rstd = rsqrtf(var + 1e-5f);
  ushort_t* orow = out + (size_t)r * D_MODEL;
  orow[tid]       = f2b(t0 * rstd * w[tid] + b[tid]);
  orow[tid + 256] = f2b(t1 * rstd * w[tid + 256] + b[tid + 256]);
  orow[tid + 512] = f2b(t2 * rstd * w[tid + 512] + b[tid + 512]);
}

// ---------- weight transpose + cast fp32[R,C] -> bf16[C,R], per-layer via z ----------
__global__ void transpose_cast_kernel(const float* __restrict__ in, ushort_t* __restrict__ out,
                                      int R, int C) {
  __shared__ float tile[32][33];
  size_t zoff = (size_t)blockIdx.z * R * C;
  in += zoff; out += zoff;
  int c0 = blockIdx.x * 32, r0 = blockIdx.y * 32;
  int tx = threadIdx.x, ty = threadIdx.y;  // blockDim (32,8)
#pragma unroll
  for (int i = 0; i < 4; i++)
    tile[ty + i * 8][tx] = in[(size_t)(r0 + ty + i * 8) * C + (c0 + tx)];
  __syncthreads();
#pragma unroll
  for (int i = 0; i < 4; i++)
    out[(size_t)(c0 + ty + i * 8) * R + (r0 + tx)] = f2b(tile[tx][ty + i * 8]);
}

// ---------- plain cast fp32 -> bf16 ----------
__global__ void cast_kernel(const float* __restrict__ in, ushort_t* __restrict__ out, int n) {
  for (int i = blockIdx.x * 256 + threadIdx.x; i < n; i += gridDim.x * 256)
    out[i] = f2b(in[i]);
}

// ---------- bf16 NT GEMM: C[M,N] = A[M,K] * B[N,K]^T, 128x128 tile, BK=32 ----------
#define EPI_STORE 0
#define EPI_ADD 1
#define EPI_GELU 2

template <int EPI>
__global__ __launch_bounds__(256) void gemm_nt(const ushort_t* __restrict__ A,
                                               const ushort_t* __restrict__ B,
                                               float* __restrict__ Cf,
                                               ushort_t* __restrict__ Cb,
                                               int M, int N, int K) {
  __shared__ __align__(16) ushort_t As[128 * 32];
  __shared__ __align__(16) ushort_t Bs[128 * 32];
  int t = threadIdx.x;
  int l = t & 63, wv = t >> 6;
  int wm = (wv >> 1) * 64, wn = (wv & 1) * 64;
  int bm = blockIdx.y, bn = blockIdx.x;
  int fr = l & 15, fq = l >> 4;

  int srow = t >> 2;         // 0..63
  int scol = (t & 3) * 8;    // bf16 elems within 32-wide K tile
  const ushort_t* gA = A + (size_t)(bm * 128 + srow) * K + scol;
  const ushort_t* gB = B + (size_t)(bn * 128 + srow) * K + scol;
  ushort_t* lA0 = &As[(wv * 16) * 32];
  ushort_t* lA1 = &As[(64 + wv * 16) * 32];
  ushort_t* lB0 = &Bs[(wv * 16) * 32];
  ushort_t* lB1 = &Bs[(64 + wv * 16) * 32];

  f32x4 acc[4][4];
#pragma unroll
  for (int i = 0; i < 4; i++)
#pragma unroll
    for (int j = 0; j < 4; j++) acc[i][j] = (f32x4){0.f, 0.f, 0.f, 0.f};

  for (int kt = 0; kt < K; kt += 32) {
    gload_lds16(gA + kt, lA0);
    gload_lds16(gA + (size_t)64 * K + kt, lA1);
    gload_lds16(gB + kt, lB0);
    gload_lds16(gB + (size_t)64 * K + kt, lB1);
    __syncthreads();
    short8 af[4], bf[4];
#pragma unroll
    for (int i = 0; i < 4; i++)
      af[i] = *(const short8*)&As[(wm + i * 16 + fr) * 32 + fq * 8];
#pragma unroll
    for (int j = 0; j < 4; j++)
      bf[j] = *(const short8*)&Bs[(wn + j * 16 + fr) * 32 + fq * 8];
#pragma unroll
    for (int i = 0; i < 4; i++)
#pragma unroll
      for (int j = 0; j < 4; j++)
        acc[i][j] = __builtin_amdgcn_mfma_f32_16x16x32_bf16(af[i], bf[j], acc[i][j], 0, 0, 0);
    __syncthreads();
  }

  // C/D layout: col = lane&15, row = (lane>>4)*4 + reg
  int row0 = bm * 128 + wm + fq * 4;
  int col0 = bn * 128 + wn + fr;
#pragma unroll
  for (int i = 0; i < 4; i++) {
#pragma unroll
    for (int j = 0; j < 4; j++) {
#pragma unroll
      for (int r = 0; r < 4; r++) {
        int row = row0 + i * 16 + r;
        int col = col0 + j * 16;
        size_t off = (size_t)row * N + col;
        float v = acc[i][j][r];
        if (EPI == EPI_STORE) {
          Cf[off] = v;
        } else if (EPI == EPI_ADD) {
          Cf[off] += v;
        } else {  // exact GELU -> bf16
          Cb[off] = f2b(0.5f * v * (1.f + erff(v * 0.70710678118f)));
        }
      }
    }
  }
}

// ---------- attention: wave per query row, online softmax, fp32 ----------
__global__ __launch_bounds__(256) void attn_kernel(const float* __restrict__ qkv,
                                                   ushort_t* __restrict__ y) {
  __shared__ __align__(16) float Ks[64 * 68];
  __shared__ __align__(16) float Vs[64 * 68];
  int t = threadIdx.x, l = t & 63, wv = t >> 6;
  int q0 = (blockIdx.x & 511) * 4;     // T/4 = 512 groups
  int bh = blockIdx.x >> 9;
  int b = bh / H_HEADS, h = bh % H_HEADS;
  size_t bT = (size_t)b * T_SEQ;
  int q = q0 + wv;
  int qmax = q0 + 3;
  const float* qrow = qkv + (bT + q) * 2304 + h * 64;
  float qv = qrow[l] * 0.125f;  // 1/sqrt(64) folded into q
  float mrun = -INFINITY, lrun = 0.f, o = 0.f;
  const float* kbase = qkv + bT * 2304 + 768 + h * 64;
  const float* vbase = qkv + bT * 2304 + 1536 + h * 64;

  for (int j0 = 0; j0 <= qmax; j0 += 64) {
    int nload = min(64, qmax - j0 + 1);
    for (int e = t; e < nload * 64; e += 256) {
      int rr = e >> 6, dd = e & 63;
      size_t goff = (size_t)(j0 + rr) * 2304 + dd;
      Ks[rr * 68 + dd] = kbase[goff];
      Vs[rr * 68 + dd] = vbase[goff];
    }
    __syncthreads();
    int kvalid = min(nload, q - j0 + 1);  // wave-uniform
    if (kvalid > 0) {
      // scores: lane l handles key j0+l (all lanes execute; mask after)
      float acc = 0.f;
      const float* kr = &Ks[l * 68];
#pragma unroll
      for (int d0 = 0; d0 < 64; d0 += 4) {
        float4 k4 = *(const float4*)(kr + d0);
        acc += __shfl(qv, d0, 64) * k4.x;
        acc += __shfl(qv, d0 + 1, 64) * k4.y;
        acc += __shfl(qv, d0 + 2, 64) * k4.z;
        acc += __shfl(qv, d0 + 3, 64) * k4.w;
      }
      float s = (l < kvalid) ? acc : -INFINITY;
      float smax = s;
#pragma unroll
      for (int m = 32; m >= 1; m >>= 1) smax = fmaxf(smax, __shfl_xor(smax, m, 64));
      float m_new = fmaxf(mrun, smax);
      float p = expf(s - m_new);   // -inf -> 0
      float psum = p;
#pragma unroll
      for (int m = 32; m >= 1; m >>= 1) psum += __shfl_xor(psum, m, 64);
      float alpha = expf(mrun - m_new);
      lrun = lrun * alpha + psum;
      mrun = m_new;
      o *= alpha;
      for (int ll = 0; ll < kvalid; ll++) {
        float pv = __shfl(p, ll, 64);
        o += pv * Vs[ll * 68 + l];
      }
    }
    __syncthreads();
  }
  y[(bT + q) * D_MODEL + h * 64 + l] = f2b(o / lrun);
}

// ---------- launch ----------
extern "C" void kernel_launch(void* const* d_in, const int* in_sizes, int n_in,
                              void* d_out, int out_size, void* d_ws, size_t ws_size,
                              hipStream_t stream) {
  const int*   idx     = (const int*)d_in[0];
  const float* tok_emb = (const float*)d_in[1];
  const float* pos_emb = (const float*)d_in[2];
  const float* ln1_w   = (const float*)d_in[3];
  const float* ln1_b   = (const float*)d_in[4];
  const float* qkv_w   = (const float*)d_in[5];
  const float* out_w   = (const float*)d_in[6];
  const float* ln2_w   = (const float*)d_in[7];
  const float* ln2_b   = (const float*)d_in[8];
  const float* ff1_w   = (const float*)d_in[9];
  const float* ff2_w   = (const float*)d_in[10];
  const float* lnf_w   = (const float*)d_in[11];
  const float* lnf_b   = (const float*)d_in[12];
  float* out = (float*)d_out;

  // workspace layout (~212 MiB)
  char* ws = (char*)d_ws;
  ushort_t* WqkvT = (ushort_t*)ws; ws += (size_t)L_LAYERS * 2304 * 768 * 2;
  ushort_t* WoutT = (ushort_t*)ws; ws += (size_t)L_LAYERS * 768 * 768 * 2;
  ushort_t* W1T   = (ushort_t*)ws; ws += (size_t)L_LAYERS * 3072 * 768 * 2;
  ushort_t* W2T   = (ushort_t*)ws; ws += (size_t)L_LAYERS * 768 * 3072 * 2;
  ushort_t* EmbB  = (ushort_t*)ws; ws += (size_t)V_VOCAB * 768 * 2;
  float*    x     = (float*)ws;    ws += (size_t)N_TOK * 768 * 4;
  ushort_t* hbuf  = (ushort_t*)ws; ws += (size_t)N_TOK * 768 * 2;
  float*    qkv   = (float*)ws;    ws += (size_t)N_TOK * 2304 * 4;
  ushort_t* ybuf  = (ushort_t*)ws; ws += (size_t)N_TOK * 768 * 2;
  ushort_t* abuf  = (ushort_t*)ws; ws += (size_t)N_TOK * 3072 * 2;

  dim3 tb(32, 8);
  transpose_cast_kernel<<<dim3(2304 / 32, 768 / 32, 6), tb, 0, stream>>>(qkv_w, WqkvT, 768, 2304);
  transpose_cast_kernel<<<dim3(768 / 32, 768 / 32, 6), tb, 0, stream>>>(out_w, WoutT, 768, 768);
  transpose_cast_kernel<<<dim3(3072 / 32, 768 / 32, 6), tb, 0, stream>>>(ff1_w, W1T, 768, 3072);
  transpose_cast_kernel<<<dim3(768 / 32, 3072 / 32, 6), tb, 0, stream>>>(ff2_w, W2T, 3072, 768);
  cast_kernel<<<12000, 256, 0, stream>>>(tok_emb, EmbB, V_VOCAB * 768);
  embed_kernel<<<N_TOK, 256, 0, stream>>>(idx, tok_emb, pos_emb, x);

  for (int layer = 0; layer < L_LAYERS; layer++) {
    ln_kernel<<<N_TOK, 256, 0, stream>>>(x, ln1_w + layer * 768, ln1_b + layer * 768, hbuf);
    gemm_nt<EPI_STORE><<<dim3(2304 / 128, N_TOK / 128), 256, 0, stream>>>(
        hbuf, WqkvT + (size_t)layer * 2304 * 768, qkv, nullptr, N_TOK, 2304, 768);
    attn_kernel<<<24 * 512, 256, 0, stream>>>(qkv, ybuf);
    gemm_nt<EPI_ADD><<<dim3(768 / 128, N_TOK / 128), 256, 0, stream>>>(
        ybuf, WoutT + (size_t)layer * 768 * 768, x, nullptr, N_TOK, 768, 768);
    ln_kernel<<<N_TOK, 256, 0, stream>>>(x, ln2_w + layer * 768, ln2_b + layer * 768, hbuf);
    gemm_nt<EPI_GELU><<<dim3(3072 / 128, N_TOK / 128), 256, 0, stream>>>(
        hbuf, W1T + (size_t)layer * 3072 * 768, nullptr, abuf, N_TOK, 3072, 768);
    gemm_nt<EPI_ADD><<<dim3(768 / 128, N_TOK / 128), 256, 0, stream>>>(
        abuf, W2T + (size_t)layer * 768 * 3072, x, nullptr, N_TOK, 768, 3072);
  }
  ln_kernel<<<N_TOK, 256, 0, stream>>>(x, lnf_w, lnf_b, hbuf);
  gemm_nt<EPI_STORE><<<dim3(V_VOCAB / 128, N_TOK / 128), 256, 0, stream>>>(
      hbuf, EmbB, out, nullptr, N_TOK, V_VOCAB, 768);
}